// Round 1
// baseline (325.598 us; speedup 1.0000x reference)
//
#include <hip/hip_runtime.h>
#include <math.h>

#define BB 2
#define PP 4096
#define CC 64
#define SZ 128
#define KK 8

// radius = 1.5/128*2 = 0.0234375 (exact); r^2 = 9*2^-14 (exact)
#define R2f 0.00054931640625f

// ---------------- Kernel 1: rasterize, per-pixel K-buffer ----------------
__global__ __launch_bounds__(256) void rast_kernel(const float* __restrict__ pts,
                                                   float* __restrict__ wbuf,
                                                   int* __restrict__ ibuf,
                                                   float* __restrict__ bg0) {
    const int tid = blockIdx.x * 256 + threadIdx.x;   // 0 .. B*H*W-1
    const int b = tid >> 14;                          // 16384 px / batch
    const int pix = tid & 16383;
    const int h = pix >> 7;
    const int w = pix & 127;
    // pixel-center NDC (exact in f32: powers of two)
    const float gx = 1.0f - 2.0f * (w + 0.5f) / 128.0f;
    const float gy = 1.0f - 2.0f * (h + 0.5f) / 128.0f;

    float zk[KK], dk[KK];
    int ik[KK];
#pragma unroll
    for (int s = 0; s < KK; ++s) { zk[s] = INFINITY; dk[s] = 0.0f; ik[s] = -1; }

    __shared__ float sx[256], sy[256], sz[256];
    const float* pb = pts + b * (PP * 3);

    for (int base = 0; base < PP; base += 256) {
        __syncthreads();
        const int p = base + threadIdx.x;
        sx[threadIdx.x] = pb[p * 3 + 0];
        sy[threadIdx.x] = pb[p * 3 + 1];
        sz[threadIdx.x] = pb[p * 3 + 2];
        __syncthreads();
#pragma unroll 8
        for (int j = 0; j < 256; ++j) {
            // ref: x = -p0, dx = gx - x = gx + p0 (negation exact)
            const float dx = __fadd_rn(gx, sx[j]);
            const float dy = __fadd_rn(gy, sy[j]);
            const float d2 = __fadd_rn(__fmul_rn(dx, dx), __fmul_rn(dy, dy));
            const float z = sz[j];
            if (d2 < R2f && z > 0.0f) {
                float zn = z, dn = d2;
                int in_ = base + j;
#pragma unroll
                for (int s = 0; s < KK; ++s) {
                    if (zn < zk[s]) {   // strict <: stable tie-break (lower idx first)
                        float tz = zk[s]; zk[s] = zn; zn = tz;
                        float td = dk[s]; dk[s] = dn; dn = td;
                        int   ti = ik[s]; ik[s] = in_; in_ = ti;
                    }
                }
            }
        }
    }

    // blending weights, front-to-back
    float T = 1.0f;
#pragma unroll
    for (int s = 0; s < KK; ++s) {
        float a = 0.0f;
        if (ik[s] >= 0) {
            float dn = dk[s] / R2f;
            dn = fminf(fmaxf(dn, 0.001f), 1.0f);
            a = 1.0f - sqrtf(dn);
        }
        const float wt = a * T;
        T = T * (1.0f - a);
        wbuf[tid * KK + s] = wt;
        ibuf[tid * KK + s] = ik[s];
    }
    bg0[tid] = (ik[0] < 0) ? 1.0f : 0.0f;
}

// ---------------- Kernel 2: composite features ----------------
__global__ __launch_bounds__(256) void composite_kernel(const float* __restrict__ src,
                                                        const float* __restrict__ wbuf,
                                                        const int* __restrict__ ibuf,
                                                        float* __restrict__ out) {
    const int t = blockIdx.x * 256 + threadIdx.x;   // 0 .. B*C*H*W-1, w fastest
    const int w = t & 127;
    const int h = (t >> 7) & 127;
    const int c = (t >> 14) & 63;
    const int b = t >> 20;
    const int pix = (b << 14) | (h << 7) | w;
    const float* srow = src + (b * CC + c) * PP;
    float acc = 0.0f;
#pragma unroll
    for (int s = 0; s < KK; ++s) {
        const int idx = ibuf[pix * KK + s];
        if (idx < 0) break;            // valid slots form a prefix (inf z sinks)
        acc = fmaf(wbuf[pix * KK + s], srow[idx], acc);
    }
    out[t] = acc;
}

// ---------------- Kernel 3: background mask, 3x3 max dilation ----------------
__global__ __launch_bounds__(256) void bg_kernel(const float* __restrict__ bg0,
                                                 float* __restrict__ bg) {
    const int t = blockIdx.x * 256 + threadIdx.x;   // 0 .. B*H*W-1
    const int w = t & 127;
    const int h = (t >> 7) & 127;
    const int b = t >> 14;
    float m = 0.0f;
#pragma unroll
    for (int dh = -1; dh <= 1; ++dh) {
#pragma unroll
        for (int dw = -1; dw <= 1; ++dw) {
            const int hh = h + dh, ww = w + dw;
            if (hh >= 0 && hh < 128 && ww >= 0 && ww < 128)
                m = fmaxf(m, bg0[(b << 14) | (hh << 7) | ww]);
        }
    }
    bg[t] = (m > 0.0f) ? 1.0f : 0.0f;
}

extern "C" void kernel_launch(void* const* d_in, const int* in_sizes, int n_in,
                              void* d_out, int out_size, void* d_ws, size_t ws_size,
                              hipStream_t stream) {
    const float* pts = (const float*)d_in[0];   // [B,P,3]
    const float* src = (const float*)d_in[1];   // [B,C,P]
    float* out = (float*)d_out;                 // [B,C,H,W] then bg [B,H,W]

    const int npix = BB * SZ * SZ;              // 32768
    float* wbuf = (float*)d_ws;                           // npix*K floats
    int*   ibuf = (int*)((char*)d_ws + npix * KK * 4);    // npix*K ints
    float* bg0  = (float*)((char*)d_ws + 2u * npix * KK * 4);  // npix floats

    rast_kernel<<<npix / 256, 256, 0, stream>>>(pts, wbuf, ibuf, bg0);
    composite_kernel<<<(BB * CC * SZ * SZ) / 256, 256, 0, stream>>>(src, wbuf, ibuf, out);
    bg_kernel<<<npix / 256, 256, 0, stream>>>(bg0, out + BB * CC * SZ * SZ);
}

// Round 2
// 48.944 us; speedup vs baseline: 6.6525x; 6.6525x over previous
//
#include <hip/hip_runtime.h>
#include <math.h>

#define BB 2
#define PP 4096
#define CC 64
#define SZ 128
#define KK 8

// radius = 1.5/128*2 = 0.0234375 (exact); r^2 = 9*2^-14 (exact)
#define R2f 0.00054931640625f
#define MAXL 256          // per-tile point-list cap (avg ~31, +20 sigma safe)
#define CG 8              // channels per composite thread

// ---------------- Kernel 1: bin (stream-compact) + rasterize per 8x8 tile ----
// block = 64 threads = 1 wave = one 8x8 pixel tile. grid = B * 16 * 16 = 512.
__global__ __launch_bounds__(64) void rast_kernel(const float* __restrict__ pts,
                                                  float* __restrict__ wbuf,
                                                  int* __restrict__ ibuf,
                                                  float* __restrict__ bg0) {
    const int lane = threadIdx.x;            // 0..63
    const int bid  = blockIdx.x;             // 0..511
    const int b    = bid >> 8;               // 256 tiles per batch
    const int tile = bid & 255;
    const int ty = tile >> 4, tx = tile & 15;
    const int w0 = tx * 8, h0 = ty * 8;
    const int w = w0 + (lane & 7);
    const int h = h0 + (lane >> 3);
    // pixel-center NDC (exact multiples of 1/128)
    const float gx = 1.0f - (2 * w + 1) * (1.0f / 128.0f);
    const float gy = 1.0f - (2 * h + 1) * (1.0f / 128.0f);

    // conservative tile bounds: r=0.0234375 + slack for f32 rounding of gx+px
    const float M   = 0.024f;
    const float xhi = 1.0f - (2 * w0 + 1)       * (1.0f / 128.0f) + M;
    const float xlo = 1.0f - (2 * (w0 + 7) + 1) * (1.0f / 128.0f) - M;
    const float yhi = 1.0f - (2 * h0 + 1)       * (1.0f / 128.0f) + M;
    const float ylo = 1.0f - (2 * (h0 + 7) + 1) * (1.0f / 128.0f) - M;

    __shared__ float sx[MAXL], sy[MAXL], sz[MAXL];
    __shared__ int   si[MAXL];
    const float* pb = pts + b * (PP * 3);

    // ---- bin: single-wave ordered stream compaction (deterministic, idx order)
    int cnt = 0;
    for (int base = 0; base < PP; base += 64) {
        const int p = base + lane;
        const float px = pb[p * 3 + 0];
        const float py = pb[p * 3 + 1];
        const float pz = pb[p * 3 + 2];
        const float fx = -px, fy = -py;     // flipped coords (exact)
        const bool pred = (pz > 0.0f) && (fx >= xlo) && (fx <= xhi)
                                      && (fy >= ylo) && (fy <= yhi);
        const unsigned long long m = __ballot(pred);
        const int pos = cnt + __popcll(m & ((1ull << lane) - 1ull));
        if (pred && pos < MAXL) {
            sx[pos] = px; sy[pos] = py; sz[pos] = pz; si[pos] = p;
        }
        cnt += __popcll(m);
    }
    if (cnt > MAXL) cnt = MAXL;
    __syncthreads();

    // ---- rasterize: per-pixel K-buffer over the tile list (bit-exact ref test)
    float zk[KK], dk[KK];
    int ik[KK];
#pragma unroll
    for (int s = 0; s < KK; ++s) { zk[s] = INFINITY; dk[s] = 0.0f; ik[s] = -1; }

    for (int j = 0; j < cnt; ++j) {
        const float dx = __fadd_rn(gx, sx[j]);   // ref: gx - (-px)
        const float dy = __fadd_rn(gy, sy[j]);
        const float d2 = __fadd_rn(__fmul_rn(dx, dx), __fmul_rn(dy, dy));
        const float z  = sz[j];
        if (d2 < R2f && z > 0.0f) {
            float zn = z, dn = d2;
            int   in_ = si[j];
#pragma unroll
            for (int s = 0; s < KK; ++s) {
                if (zn < zk[s]) {   // strict <: stable tie-break (lower idx first)
                    float tz = zk[s]; zk[s] = zn; zn = tz;
                    float td = dk[s]; dk[s] = dn; dn = td;
                    int   ti = ik[s]; ik[s] = in_; in_ = ti;
                }
            }
        }
    }

    // ---- blending weights, front-to-back
    const int tid = (b << 14) | (h << 7) | w;
    float T = 1.0f;
#pragma unroll
    for (int s = 0; s < KK; ++s) {
        float a = 0.0f;
        if (ik[s] >= 0) {
            float dn = dk[s] / R2f;
            dn = fminf(fmaxf(dn, 0.001f), 1.0f);
            a = 1.0f - sqrtf(dn);
        }
        const float wt = a * T;
        T = T * (1.0f - a);
        wbuf[tid * KK + s] = wt;
        ibuf[tid * KK + s] = ik[s];
    }
    bg0[tid] = (ik[0] < 0) ? 1.0f : 0.0f;
}

// ---------------- Kernel 2: composite features, CG channels per thread ------
__global__ __launch_bounds__(256) void composite_kernel(const float* __restrict__ src,
                                                        const float* __restrict__ wbuf,
                                                        const int* __restrict__ ibuf,
                                                        float* __restrict__ out) {
    const int t   = blockIdx.x * 256 + threadIdx.x;  // 0 .. B*(C/CG)*16384-1
    const int pix = t & 16383;
    const int cg  = (t >> 14) & (CC / CG - 1);
    const int b   = t >> 17;                          // 14 + log2(C/CG)
    const int gpix = (b << 14) | pix;

    const int4   ia = *(const int4*)  (ibuf + gpix * KK);
    const int4   ib = *(const int4*)  (ibuf + gpix * KK + 4);
    const float4 wa = *(const float4*)(wbuf + gpix * KK);
    const float4 wb = *(const float4*)(wbuf + gpix * KK + 4);
    const int   idx[KK] = { ia.x, ia.y, ia.z, ia.w, ib.x, ib.y, ib.z, ib.w };
    const float wt [KK] = { wa.x, wa.y, wa.z, wa.w, wb.x, wb.y, wb.z, wb.w };

    const float* sb = src + (b * CC + cg * CG) * PP;
    float acc[CG];
#pragma unroll
    for (int cc = 0; cc < CG; ++cc) acc[cc] = 0.0f;

#pragma unroll
    for (int s = 0; s < KK; ++s) {
        const int id = idx[s];
        if (id < 0) break;               // valid slots form a prefix
        const float ww = wt[s];
#pragma unroll
        for (int cc = 0; cc < CG; ++cc)
            acc[cc] = fmaf(ww, sb[cc * PP + id], acc[cc]);
    }
#pragma unroll
    for (int cc = 0; cc < CG; ++cc)
        out[((b * CC + cg * CG + cc) << 14) | pix] = acc[cc];
}

// ---------------- Kernel 3: background mask, 3x3 max dilation ----------------
__global__ __launch_bounds__(256) void bg_kernel(const float* __restrict__ bg0,
                                                 float* __restrict__ bg) {
    const int t = blockIdx.x * 256 + threadIdx.x;   // 0 .. B*H*W-1
    const int w = t & 127;
    const int h = (t >> 7) & 127;
    const int b = t >> 14;
    float m = 0.0f;
#pragma unroll
    for (int dh = -1; dh <= 1; ++dh) {
#pragma unroll
        for (int dw = -1; dw <= 1; ++dw) {
            const int hh = h + dh, ww = w + dw;
            if (hh >= 0 && hh < 128 && ww >= 0 && ww < 128)
                m = fmaxf(m, bg0[(b << 14) | (hh << 7) | ww]);
        }
    }
    bg[t] = (m > 0.0f) ? 1.0f : 0.0f;
}

extern "C" void kernel_launch(void* const* d_in, const int* in_sizes, int n_in,
                              void* d_out, int out_size, void* d_ws, size_t ws_size,
                              hipStream_t stream) {
    const float* pts = (const float*)d_in[0];   // [B,P,3]
    const float* src = (const float*)d_in[1];   // [B,C,P]
    float* out = (float*)d_out;                 // [B,C,H,W] then bg [B,H,W]

    const int npix = BB * SZ * SZ;              // 32768
    float* wbuf = (float*)d_ws;                           // npix*K floats
    int*   ibuf = (int*)((char*)d_ws + npix * KK * 4);    // npix*K ints
    float* bg0  = (float*)((char*)d_ws + 2u * npix * KK * 4);  // npix floats

    rast_kernel<<<BB * 256, 64, 0, stream>>>(pts, wbuf, ibuf, bg0);
    composite_kernel<<<(BB * (CC / CG) * SZ * SZ) / 256, 256, 0, stream>>>(src, wbuf, ibuf, out);
    bg_kernel<<<npix / 256, 256, 0, stream>>>(bg0, out + BB * CC * SZ * SZ);
}

// Round 3
// 48.091 us; speedup vs baseline: 6.7705x; 1.0177x over previous
//
#include <hip/hip_runtime.h>
#include <math.h>

#define BB 2
#define PP 4096
#define CC 64
#define SZ 128
#define KK 8

// radius = 1.5/128*2 = 0.0234375 (exact); r^2 = 9*2^-14 (exact)
#define R2f 0.00054931640625f
#define MAXL 128          // per-tile list cap (mean ~31, astronomically safe)
#define CG 8              // channels per composite thread
#define NTILE 512         // B * 16 * 16

// ---------------- Kernel A: point-parallel binning ---------------------------
// One thread per point; each point touches at most 2x2 tiles (1.6px < 8px tile).
__global__ __launch_bounds__(256) void bin_kernel(const float* __restrict__ pts,
                                                  int* __restrict__ cnt,
                                                  int* __restrict__ lists) {
    const int t = blockIdx.x * 256 + threadIdx.x;
    if (t >= BB * PP) return;
    const int b = t >> 12;            // PP = 4096
    const int p = t & (PP - 1);
    const float* q = pts + (size_t)(b * PP + p) * 3;
    const float px = q[0], py = q[1], pz = q[2];
    if (!(pz > 0.0f)) return;
    // flipped coords fx=-px; pixel-space center: u = (1-fx)*64 - 0.5 = (1+px)*64 - 0.5
    const float u = (1.0f + px) * 64.0f - 0.5f;
    const float v = (1.0f + py) * 64.0f - 0.5f;
    // conservative reach: 1.5px radius + f32 slack -> 1.6px
    const int tx0 = max(0,  (int)floorf((u - 1.6f) * 0.125f));
    const int tx1 = min(15, (int)floorf((u + 1.6f) * 0.125f));
    const int ty0 = max(0,  (int)floorf((v - 1.6f) * 0.125f));
    const int ty1 = min(15, (int)floorf((v + 1.6f) * 0.125f));
    for (int ty = ty0; ty <= ty1; ++ty)
        for (int tx = tx0; tx <= tx1; ++tx) {
            const int tile = (b << 8) | (ty << 4) | tx;
            const int pos = atomicAdd(cnt + tile, 1);
            if (pos < MAXL) lists[tile * MAXL + pos] = p;
        }
}

// ---------------- Kernel B: rasterize per 8x8 tile from its list -------------
__global__ __launch_bounds__(64) void rast_kernel(const float* __restrict__ pts,
                                                  const int* __restrict__ cnt,
                                                  const int* __restrict__ lists,
                                                  float* __restrict__ wbuf,
                                                  int* __restrict__ ibuf,
                                                  float* __restrict__ bg0) {
    const int lane = threadIdx.x;            // 0..63
    const int bid  = blockIdx.x;             // 0..511
    const int b    = bid >> 8;
    const int tile = bid & 255;
    const int ty = tile >> 4, tx = tile & 15;
    const int w = tx * 8 + (lane & 7);
    const int h = ty * 8 + (lane >> 3);
    const float gx = 1.0f - (2 * w + 1) * (1.0f / 128.0f);
    const float gy = 1.0f - (2 * h + 1) * (1.0f / 128.0f);

    __shared__ int   li[MAXL], si[MAXL];
    __shared__ float sx[MAXL], sy[MAXL], sz[MAXL];

    int n = cnt[bid];
    if (n > MAXL) n = MAXL;

    for (int e = lane; e < n; e += 64) li[e] = lists[bid * MAXL + e];
    __syncthreads();
    // rank-sort by point index -> restores global index order (stable tie-break)
    for (int e = lane; e < n; e += 64) {
        const int vdx = li[e];
        int r = 0;
        for (int j = 0; j < n; ++j) r += (li[j] < vdx) ? 1 : 0;
        si[r] = vdx;
    }
    __syncthreads();
    const float* pb = pts + b * (PP * 3);
    for (int e = lane; e < n; e += 64) {
        const int p = si[e];
        sx[e] = pb[p * 3 + 0];
        sy[e] = pb[p * 3 + 1];
        sz[e] = pb[p * 3 + 2];
    }
    __syncthreads();

    // per-pixel K-buffer (bit-exact ref test, index-ordered insertion)
    float zk[KK], dk[KK];
    int ik[KK];
#pragma unroll
    for (int s = 0; s < KK; ++s) { zk[s] = INFINITY; dk[s] = 0.0f; ik[s] = -1; }

    for (int j = 0; j < n; ++j) {
        const float dx = __fadd_rn(gx, sx[j]);   // ref: gx - (-px)
        const float dy = __fadd_rn(gy, sy[j]);
        const float d2 = __fadd_rn(__fmul_rn(dx, dx), __fmul_rn(dy, dy));
        const float z  = sz[j];
        if (d2 < R2f && z > 0.0f) {
            float zn = z, dn = d2;
            int   in_ = si[j];
#pragma unroll
            for (int s = 0; s < KK; ++s) {
                if (zn < zk[s]) {   // strict <: lower idx first on z-tie
                    float tz = zk[s]; zk[s] = zn; zn = tz;
                    float td = dk[s]; dk[s] = dn; dn = td;
                    int   ti = ik[s]; ik[s] = in_; in_ = ti;
                }
            }
        }
    }

    const int tid = (b << 14) | (h << 7) | w;
    float T = 1.0f;
#pragma unroll
    for (int s = 0; s < KK; ++s) {
        float a = 0.0f;
        if (ik[s] >= 0) {
            float dn = dk[s] / R2f;
            dn = fminf(fmaxf(dn, 0.001f), 1.0f);
            a = 1.0f - sqrtf(dn);
        }
        const float wt = a * T;
        T = T * (1.0f - a);
        wbuf[tid * KK + s] = wt;
        ibuf[tid * KK + s] = ik[s];
    }
    bg0[tid] = (ik[0] < 0) ? 1.0f : 0.0f;
}

// ---------------- Kernel C: composite (CG channels/thread) + fused bg -------
__global__ __launch_bounds__(256) void composite_kernel(const float* __restrict__ src,
                                                        const float* __restrict__ wbuf,
                                                        const int* __restrict__ ibuf,
                                                        const float* __restrict__ bg0,
                                                        float* __restrict__ out,
                                                        float* __restrict__ bgout) {
    const int t   = blockIdx.x * 256 + threadIdx.x;  // 0 .. B*(C/CG)*16384-1
    const int pix = t & 16383;
    const int cg  = (t >> 14) & (CC / CG - 1);
    const int b   = t >> 17;
    const int gpix = (b << 14) | pix;

    const int4   ia = *(const int4*)  (ibuf + gpix * KK);
    const int4   ibv = *(const int4*) (ibuf + gpix * KK + 4);
    const float4 wa = *(const float4*)(wbuf + gpix * KK);
    const float4 wb = *(const float4*)(wbuf + gpix * KK + 4);
    const int   idx[KK] = { ia.x, ia.y, ia.z, ia.w, ibv.x, ibv.y, ibv.z, ibv.w };
    const float wt [KK] = { wa.x, wa.y, wa.z, wa.w, wb.x, wb.y, wb.z, wb.w };

    const float* sb = src + (b * CC + cg * CG) * PP;
    float acc[CG];
#pragma unroll
    for (int cc = 0; cc < CG; ++cc) acc[cc] = 0.0f;

#pragma unroll
    for (int s = 0; s < KK; ++s) {
        const int id = idx[s];
        if (id < 0) break;               // valid slots form a prefix
        const float ww = wt[s];
#pragma unroll
        for (int cc = 0; cc < CG; ++cc)
            acc[cc] = fmaf(ww, sb[cc * PP + id], acc[cc]);
    }
#pragma unroll
    for (int cc = 0; cc < CG; ++cc)
        out[((b * CC + cg * CG + cc) << 14) | pix] = acc[cc];

    // fused background dilation: 1/8 of threads (cg==0) handle their pixel
    if (cg == 0) {
        const int w = pix & 127;
        const int h = pix >> 7;
        float m = 0.0f;
#pragma unroll
        for (int dh = -1; dh <= 1; ++dh)
#pragma unroll
            for (int dw = -1; dw <= 1; ++dw) {
                const int hh = h + dh, ww = w + dw;
                if (hh >= 0 && hh < 128 && ww >= 0 && ww < 128)
                    m = fmaxf(m, bg0[(b << 14) | (hh << 7) | ww]);
            }
        bgout[gpix] = (m > 0.0f) ? 1.0f : 0.0f;
    }
}

extern "C" void kernel_launch(void* const* d_in, const int* in_sizes, int n_in,
                              void* d_out, int out_size, void* d_ws, size_t ws_size,
                              hipStream_t stream) {
    const float* pts = (const float*)d_in[0];   // [B,P,3]
    const float* src = (const float*)d_in[1];   // [B,C,P]
    float* out = (float*)d_out;                 // [B,C,H,W] then bg [B,H,W]

    const int npix = BB * SZ * SZ;              // 32768
    char* ws = (char*)d_ws;
    float* wbuf  = (float*)ws;                                   // npix*K f32 (1MB)
    int*   ibuf  = (int*)(ws + (size_t)npix * KK * 4);           // npix*K i32 (1MB)
    float* bg0   = (float*)(ws + 2u * npix * KK * 4);            // npix f32 (128KB)
    int*   cnt   = (int*)(ws + 2u * npix * KK * 4 + npix * 4);   // 512 i32
    int*   lists = cnt + NTILE;                                  // 512*MAXL i32 (256KB)

    hipMemsetAsync(cnt, 0, NTILE * sizeof(int), stream);
    bin_kernel<<<(BB * PP) / 256, 256, 0, stream>>>(pts, cnt, lists);
    rast_kernel<<<NTILE, 64, 0, stream>>>(pts, cnt, lists, wbuf, ibuf, bg0);
    composite_kernel<<<(BB * (CC / CG) * SZ * SZ) / 256, 256, 0, stream>>>(
        src, wbuf, ibuf, bg0, out, out + BB * CC * SZ * SZ);
}

// Round 4
// 39.395 us; speedup vs baseline: 8.2650x; 1.2207x over previous
//
#include <hip/hip_runtime.h>
#include <math.h>

#define BB 2
#define PP 4096
#define CC 64
#define SZ 128
#define KK 8

// radius = 1.5/128*2 = 0.0234375 (exact); r^2 = 9*2^-14 (exact)
#define R2f 0.00054931640625f
#define SEGCAP 96         // per-wave segment cap (mean ~7.8, +30 sigma safe)
#define CG 8              // channels per composite thread
#define NTILE 512         // B * 16 * 16

// ---------------- Kernel 1: fused bin + rasterize, one block per 8x8 tile ----
// 4 waves: wave w ballot-compacts points [1024w, 1024w+1024) into LDS segment w
// (index order preserved); concat of segments is globally index-ascending.
// Wave 0 then rasterizes the tile's list with the bit-exact reference test.
__global__ __launch_bounds__(256) void rast_kernel(const float* __restrict__ pts,
                                                   float* __restrict__ wbuf,
                                                   int* __restrict__ ibuf,
                                                   float* __restrict__ bg0) {
    const int tidb = threadIdx.x;
    const int wave = tidb >> 6;              // 0..3
    const int lane = tidb & 63;
    const int bid  = blockIdx.x;             // 0..511
    const int b    = bid >> 8;
    const int tile = bid & 255;
    const int ty = tile >> 4, tx = tile & 15;
    const int w0 = tx * 8, h0 = ty * 8;

    // conservative tile bounds in flipped NDC: r=0.0234375 + f32 slack
    const float M   = 0.024f;
    const float xhi = 1.0f - (2 * w0 + 1)       * (1.0f / 128.0f) + M;
    const float xlo = 1.0f - (2 * (w0 + 7) + 1) * (1.0f / 128.0f) - M;
    const float yhi = 1.0f - (2 * h0 + 1)       * (1.0f / 128.0f) + M;
    const float ylo = 1.0f - (2 * (h0 + 7) + 1) * (1.0f / 128.0f) - M;

    __shared__ float sx[4][SEGCAP], sy[4][SEGCAP], sz[4][SEGCAP];
    __shared__ int   si[4][SEGCAP];
    __shared__ int   scnt[4];

    const float* pb = pts + b * (PP * 3);

    // ---- phase A: per-wave ordered ballot compaction over its index quarter
    int cnt = 0;
    const int pbase = wave * (PP / 4);
#pragma unroll 4
    for (int it = 0; it < (PP / 4); it += 64) {
        const int p = pbase + it + lane;
        const float px = pb[p * 3 + 0];
        const float py = pb[p * 3 + 1];
        const float pz = pb[p * 3 + 2];
        const float fx = -px, fy = -py;     // flipped coords (exact)
        const bool pred = (pz > 0.0f) && (fx >= xlo) && (fx <= xhi)
                                      && (fy >= ylo) && (fy <= yhi);
        const unsigned long long m = __ballot(pred);
        const int pos = cnt + __popcll(m & ((1ull << lane) - 1ull));
        if (pred && pos < SEGCAP) {
            sx[wave][pos] = px; sy[wave][pos] = py;
            sz[wave][pos] = pz; si[wave][pos] = p;
        }
        cnt += __popcll(m);
    }
    if (lane == 0) scnt[wave] = (cnt > SEGCAP) ? SEGCAP : cnt;
    __syncthreads();

    // ---- phase B: wave 0 rasterizes 64 pixels against the concatenated list
    if (wave == 0) {
        const int w = w0 + (lane & 7);
        const int h = h0 + (lane >> 3);
        const float gx = 1.0f - (2 * w + 1) * (1.0f / 128.0f);
        const float gy = 1.0f - (2 * h + 1) * (1.0f / 128.0f);

        float zk[KK], dk[KK];
        int ik[KK];
#pragma unroll
        for (int s = 0; s < KK; ++s) { zk[s] = INFINITY; dk[s] = 0.0f; ik[s] = -1; }

#pragma unroll 1
        for (int sg = 0; sg < 4; ++sg) {
            const int n = scnt[sg];
            for (int j = 0; j < n; ++j) {
                const float dx = __fadd_rn(gx, sx[sg][j]);   // ref: gx - (-px)
                const float dy = __fadd_rn(gy, sy[sg][j]);
                const float d2 = __fadd_rn(__fmul_rn(dx, dx), __fmul_rn(dy, dy));
                const float z  = sz[sg][j];
                if (d2 < R2f && z > 0.0f) {
                    float zn = z, dn = d2;
                    int   in_ = si[sg][j];
#pragma unroll
                    for (int s = 0; s < KK; ++s) {
                        if (zn < zk[s]) {   // strict <: lower idx first on z-tie
                            float tz = zk[s]; zk[s] = zn; zn = tz;
                            float td = dk[s]; dk[s] = dn; dn = td;
                            int   ti = ik[s]; ik[s] = in_; in_ = ti;
                        }
                    }
                }
            }
        }

        const int tid = (b << 14) | (h << 7) | w;
        float T = 1.0f;
#pragma unroll
        for (int s = 0; s < KK; ++s) {
            float a = 0.0f;
            if (ik[s] >= 0) {
                float dn = dk[s] / R2f;
                dn = fminf(fmaxf(dn, 0.001f), 1.0f);
                a = 1.0f - sqrtf(dn);
            }
            const float wt = a * T;
            T = T * (1.0f - a);
            wbuf[tid * KK + s] = wt;
            ibuf[tid * KK + s] = ik[s];
        }
        bg0[tid] = (ik[0] < 0) ? 1.0f : 0.0f;
    }
}

// ---------------- Kernel 2: composite (CG channels/thread) + fused bg -------
__global__ __launch_bounds__(256) void composite_kernel(const float* __restrict__ src,
                                                        const float* __restrict__ wbuf,
                                                        const int* __restrict__ ibuf,
                                                        const float* __restrict__ bg0,
                                                        float* __restrict__ out,
                                                        float* __restrict__ bgout) {
    const int t   = blockIdx.x * 256 + threadIdx.x;  // 0 .. B*(C/CG)*16384-1
    const int pix = t & 16383;
    const int cg  = (t >> 14) & (CC / CG - 1);
    const int b   = t >> 17;
    const int gpix = (b << 14) | pix;

    const int4   ia  = *(const int4*)  (ibuf + gpix * KK);
    const int4   ibv = *(const int4*)  (ibuf + gpix * KK + 4);
    const float4 wa  = *(const float4*)(wbuf + gpix * KK);
    const float4 wb  = *(const float4*)(wbuf + gpix * KK + 4);
    const int   idx[KK] = { ia.x, ia.y, ia.z, ia.w, ibv.x, ibv.y, ibv.z, ibv.w };
    const float wt [KK] = { wa.x, wa.y, wa.z, wa.w, wb.x, wb.y, wb.z, wb.w };

    const float* sb = src + (b * CC + cg * CG) * PP;
    float acc[CG];
#pragma unroll
    for (int cc = 0; cc < CG; ++cc) acc[cc] = 0.0f;

#pragma unroll
    for (int s = 0; s < KK; ++s) {
        const int id = idx[s];
        if (id < 0) break;               // valid slots form a prefix
        const float ww = wt[s];
#pragma unroll
        for (int cc = 0; cc < CG; ++cc)
            acc[cc] = fmaf(ww, sb[cc * PP + id], acc[cc]);
    }
#pragma unroll
    for (int cc = 0; cc < CG; ++cc)
        out[((b * CC + cg * CG + cc) << 14) | pix] = acc[cc];

    // fused background dilation: 1/8 of threads (cg==0) handle their pixel
    if (cg == 0) {
        const int w = pix & 127;
        const int h = pix >> 7;
        float m = 0.0f;
#pragma unroll
        for (int dh = -1; dh <= 1; ++dh)
#pragma unroll
            for (int dw = -1; dw <= 1; ++dw) {
                const int hh = h + dh, ww = w + dw;
                if (hh >= 0 && hh < 128 && ww >= 0 && ww < 128)
                    m = fmaxf(m, bg0[(b << 14) | (hh << 7) | ww]);
            }
        bgout[gpix] = (m > 0.0f) ? 1.0f : 0.0f;
    }
}

extern "C" void kernel_launch(void* const* d_in, const int* in_sizes, int n_in,
                              void* d_out, int out_size, void* d_ws, size_t ws_size,
                              hipStream_t stream) {
    const float* pts = (const float*)d_in[0];   // [B,P,3]
    const float* src = (const float*)d_in[1];   // [B,C,P]
    float* out = (float*)d_out;                 // [B,C,H,W] then bg [B,H,W]

    const int npix = BB * SZ * SZ;              // 32768
    char* ws = (char*)d_ws;
    float* wbuf = (float*)ws;                                // npix*K f32 (1MB)
    int*   ibuf = (int*)(ws + (size_t)npix * KK * 4);        // npix*K i32 (1MB)
    float* bg0  = (float*)(ws + 2u * (size_t)npix * KK * 4); // npix f32 (128KB)

    rast_kernel<<<NTILE, 256, 0, stream>>>(pts, wbuf, ibuf, bg0);
    composite_kernel<<<(BB * (CC / CG) * SZ * SZ) / 256, 256, 0, stream>>>(
        src, wbuf, ibuf, bg0, out, out + BB * CC * SZ * SZ);
}

// Round 5
// 31.328 us; speedup vs baseline: 10.3932x; 1.2575x over previous
//
#include <hip/hip_runtime.h>
#include <math.h>

#define BB 2
#define PP 4096
#define CC 64
#define SZ 128
#define KK 8

// radius = 1.5/128*2 = 0.0234375 (exact); r^2 = 9*2^-14 (exact)
#define R2f 0.00054931640625f
#define SLOTS 20          // per-pixel slot cap (mean hits ~1.8, P(>=20) ~ 0)
#define CG 8              // channels per composite thread

typedef unsigned long long u64;

// ---------------- Kernel A: point-parallel exact binning --------------------
// 4 threads per point; thread r handles candidate pixel-row (hlo + r).
// Total candidate tests ~ 98k (vs 2M tile tests in the scan approach).
__global__ __launch_bounds__(256) void bin_kernel(const float* __restrict__ pts,
                                                  int* __restrict__ cnt,
                                                  u64* __restrict__ keys,
                                                  float* __restrict__ d2s) {
    const int t  = blockIdx.x * 256 + threadIdx.x;   // 0 .. BB*PP*4-1
    const int r  = t & 3;
    const int gp = t >> 2;                           // 0 .. BB*PP-1
    const int b  = gp >> 12;                         // PP = 4096
    const int p  = gp & (PP - 1);
    const float* q = pts + (size_t)gp * 3;
    const float px = q[0], py = q[1], pz = q[2];
    if (!(pz > 0.0f)) return;
    // gx(w) = 1-(2w+1)/128 equals -px at w = (1+px)*64 - 0.5
    const float u = (1.0f + px) * 64.0f - 0.5f;
    const float v = (1.0f + py) * 64.0f - 0.5f;
    // |w-u| < 1.5 px (+0.03 slack for f32 rounding); exact test filters below
    const int wlo = max(0,   (int)ceilf (u - 1.53f));
    const int whi = min(127, (int)floorf(u + 1.53f));
    const int hlo = max(0,   (int)ceilf (v - 1.53f));
    const int hhi = min(127, (int)floorf(v + 1.53f));
    const int h = hlo + r;
    if (h > hhi || wlo > whi) return;

    const float gy  = 1.0f - (2 * h + 1) * (1.0f / 128.0f);
    const float dy  = __fadd_rn(gy, py);             // ref: gy - (-py)
    const float dy2 = __fmul_rn(dy, dy);
    const u64 zkey = ((u64)__float_as_uint(pz) << 32) | (unsigned)p;

    for (int w = wlo; w <= whi; ++w) {
        const float gx = 1.0f - (2 * w + 1) * (1.0f / 128.0f);
        const float dx = __fadd_rn(gx, px);
        const float d2 = __fadd_rn(__fmul_rn(dx, dx), dy2);   // bit-exact ref d2
        if (d2 < R2f) {
            const int pix = (b << 14) | (h << 7) | w;
            const int pos = atomicAdd(cnt + pix, 1);
            if (pos < SLOTS) {
                keys[pix * SLOTS + pos] = zkey;
                d2s [pix * SLOTS + pos] = d2;
            }
        }
    }
}

// ------- Kernel B: fused select (8-deep K-buffer) + weights + composite + bg
__global__ __launch_bounds__(256) void selcomp_kernel(const float* __restrict__ src,
                                                      const int* __restrict__ cnt,
                                                      const u64* __restrict__ keys,
                                                      const float* __restrict__ d2s,
                                                      float* __restrict__ out,
                                                      float* __restrict__ bgout) {
    const int t   = blockIdx.x * 256 + threadIdx.x;  // 0 .. BB*(CC/CG)*16384-1
    const int pix = t & 16383;
    const int cg  = (t >> 14) & (CC / CG - 1);
    const int b   = t >> 17;
    const int gpix = (b << 14) | pix;

    int n = cnt[gpix];
    n = (n > SLOTS) ? SLOTS : n;

    // K smallest (z, idx) via 8-deep sorted insertion on the packed u64 key.
    // Keys are unique => deterministic regardless of atomic slot order.
    u64   kk[KK];
    float dd[KK];
#pragma unroll
    for (int s = 0; s < KK; ++s) { kk[s] = ~0ull; dd[s] = 0.0f; }
    for (int j = 0; j < n; ++j) {
        u64   kn = keys[gpix * SLOTS + j];
        float dn = d2s [gpix * SLOTS + j];
#pragma unroll
        for (int s = 0; s < KK; ++s) {
            if (kn < kk[s]) {
                u64   tk = kk[s]; kk[s] = kn; kn = tk;
                float td = dd[s]; dd[s] = dn; dn = td;
            }
        }
    }

    const float* sb = src + (b * CC + cg * CG) * PP;
    float acc[CG];
#pragma unroll
    for (int cc = 0; cc < CG; ++cc) acc[cc] = 0.0f;

    float T = 1.0f;
#pragma unroll
    for (int s = 0; s < KK; ++s) {
        if (kk[s] == ~0ull) break;       // filled slots form a prefix
        const int id = (int)(kk[s] & 0xffffffffu);
        float dn = dd[s] / R2f;          // same FP path as passing rounds
        dn = fminf(fmaxf(dn, 0.001f), 1.0f);
        const float a  = 1.0f - sqrtf(dn);
        const float wt = a * T;
        T = T * (1.0f - a);
#pragma unroll
        for (int cc = 0; cc < CG; ++cc)
            acc[cc] = fmaf(wt, sb[cc * PP + id], acc[cc]);
    }
#pragma unroll
    for (int cc = 0; cc < CG; ++cc)
        out[((b * CC + cg * CG + cc) << 14) | pix] = acc[cc];

    // background: dilate(cnt==0) over 3x3 — cnt fully determines slot-0-empty
    if (cg == 0) {
        const int w = pix & 127;
        const int h = pix >> 7;
        int bgv = 0;
#pragma unroll
        for (int dh = -1; dh <= 1; ++dh)
#pragma unroll
            for (int dw = -1; dw <= 1; ++dw) {
                const int hh = h + dh, ww = w + dw;
                if (hh >= 0 && hh < 128 && ww >= 0 && ww < 128)
                    if (cnt[(b << 14) | (hh << 7) | ww] == 0) bgv = 1;
            }
        bgout[gpix] = bgv ? 1.0f : 0.0f;
    }
}

extern "C" void kernel_launch(void* const* d_in, const int* in_sizes, int n_in,
                              void* d_out, int out_size, void* d_ws, size_t ws_size,
                              hipStream_t stream) {
    const float* pts = (const float*)d_in[0];   // [B,P,3]
    const float* src = (const float*)d_in[1];   // [B,C,P]
    float* out = (float*)d_out;                 // [B,C,H,W] then bg [B,H,W]

    const int npix = BB * SZ * SZ;              // 32768
    char* ws = (char*)d_ws;
    int*   cnt  = (int*)ws;                                  // 128 KB
    u64*   keys = (u64*)(ws + (size_t)npix * 4);             // 5 MB (8B aligned)
    float* d2s  = (float*)(ws + (size_t)npix * 4 + (size_t)npix * SLOTS * 8);

    hipMemsetAsync(cnt, 0, (size_t)npix * 4, stream);
    bin_kernel<<<(BB * PP * 4) / 256, 256, 0, stream>>>(pts, cnt, keys, d2s);
    selcomp_kernel<<<(BB * (CC / CG) * SZ * SZ) / 256, 256, 0, stream>>>(
        src, cnt, keys, d2s, out, out + BB * CC * SZ * SZ);
}